// Round 19
// baseline (137.485 us; speedup 1.0000x reference)
//
#include <hip/hip_runtime.h>
#include <hip/hip_bf16.h>
#include <math.h>

#define L_SEQ 4096
#define DIM   1024
#define NH    16
#define HD    64

// 0.125 * log2(e): folded into Q so QK^T lands in the exp2 domain pre-scaled.
#define QSCL 0.18033688011112042f

typedef __attribute__((ext_vector_type(4)))  float f32x4;
typedef __attribute__((ext_vector_type(16))) float f32x16;
typedef __attribute__((ext_vector_type(8)))  short s16x8;
typedef __attribute__((ext_vector_type(4)))  short s16x4;
typedef __attribute__((ext_vector_type(4)))  unsigned u32x4;
typedef __attribute__((ext_vector_type(2)))  unsigned u32x2;

#if defined(__has_builtin)
#  if __has_builtin(__builtin_amdgcn_permlane32_swap)
#    define HAVE_PLSWAP 1
#  else
#    define HAVE_PLSWAP 0
#  endif
#else
#  define HAVE_PLSWAP 0
#endif

__device__ __forceinline__ short f2bf(float f) {
  unsigned u = __builtin_bit_cast(unsigned, f);
  u = u + 0x7fffu + ((u >> 16) & 1u);   // RNE
  return (short)(u >> 16);
}

__device__ __forceinline__ unsigned cvt_pk_bf16(float lo, float hi_) {
  unsigned r;
  asm("v_cvt_pk_bf16_f32 %0, %1, %2" : "=v"(r) : "v"(lo), "v"(hi_));
  return r;
}

__device__ __forceinline__ s16x8 cvt8(const f32x4 a, const f32x4 b) {
  u32x4 u;
  u[0] = cvt_pk_bf16(a[0], a[1]);
  u[1] = cvt_pk_bf16(a[2], a[3]);
  u[2] = cvt_pk_bf16(b[0], b[1]);
  u[3] = cvt_pk_bf16(b[2], b[3]);
  return __builtin_bit_cast(s16x8, u);
}

__device__ __forceinline__ float exp2_fast(float x) {
  float r;
  asm("v_exp_f32 %0, %1" : "=v"(r) : "v"(x));
  return r;
}

__device__ __forceinline__ void gload_lds16(const void* g, void* l) {
  __builtin_amdgcn_global_load_lds(
      (__attribute__((address_space(1))) void*)(g),
      (__attribute__((address_space(3))) void*)(l), 16, 0, 0);
}

// ---------------- fp32 -> bf16 convert (W_out only; x/W_qkv converted in-GEMM) --
#define CVT_N3 (DIM * DIM / 4)      // 262144

__global__ __launch_bounds__(256) void cvt_wout(const float* __restrict__ Wout,
                                                short* __restrict__ woutb) {
  int i = blockIdx.x * 256 + threadIdx.x;
  f32x4 f = *(const f32x4*)(Wout + i * 4);
  s16x4 o;
  o[0] = f2bf(f[0]); o[1] = f2bf(f[1]); o[2] = f2bf(f[2]); o[3] = f2bf(f[3]);
  *(s16x4*)(woutb + i * 4) = o;
}

// ---------------- merged QKV projection GEMM: 64x128 tile, fp32 in, 6 blocks/CU -
// Reads x and W_qkv as FP32 directly; converts to bf16 during staging via
// per-lane ds_write_b128 (LDS layout identical to round 18's passing kernel).
// Grid 1536 (64 bm x 24 bn), T1 remap: XCD x owns bm in [8x,8x+8) x all bn.
// 4 waves; wave w owns output strip [64 x 32] at n-base w*32. BK=32.
// Q/K (bn 0..15): SWAPPED mfma(bfr, af) -> C^T, vectorized stores (r17-verified).
// V (bn 16..23): normal orientation, frag-order s16x4 stores.
__global__ __launch_bounds__(256) void gemm_qkv64(const float* __restrict__ A,
                                                  const float* __restrict__ B,
                                                  const float* __restrict__ bias,
                                                  short* __restrict__ Qb,
                                                  short* __restrict__ Kf,
                                                  short* __restrict__ Vf) {
  __shared__ __align__(16) short As[64 * 32];    // 4 KB
  __shared__ __align__(16) short Bs[128 * 32];   // 8 KB
  const int t = threadIdx.x;
  const int w = t >> 6, l = t & 63;
  const int lr = l & 15, lg = l >> 4;
  const int bid = blockIdx.x;
  const int xcd = bid & 7;
  const int ii = bid >> 3;              // 0..191
  const int bm = xcd * 8 + (ii & 7);    // 0..63
  const int bn = ii >> 3;               // 0..23
  const bool isV = (bn >= 16);

  f32x4 acc[4][2];
#pragma unroll
  for (int m = 0; m < 4; ++m)
#pragma unroll
    for (int n = 0; n < 2; ++n) acc[m][n] = (f32x4)0.f;

  // staging addressing: thread t -> row t>>2, col8 = (t&3)*8
  const float* ap = A + (bm * 64 + (t >> 2)) * DIM + (t & 3) * 8;
  const float* bp = B + (bn * 128 + (t >> 2)) * DIM + (t & 3) * 8;
  short* aw = &As[(t >> 2) * 32 + (t & 3) * 8];
  short* bw0 = &Bs[(t >> 2) * 32 + (t & 3) * 8];
  short* bw1 = &Bs[(64 + (t >> 2)) * 32 + (t & 3) * 8];

  for (int kk = 0; kk < DIM; kk += 32) {
    const f32x4 a0 = *(const f32x4*)(ap + kk);
    const f32x4 a1 = *(const f32x4*)(ap + kk + 4);
    const f32x4 b0 = *(const f32x4*)(bp + kk);
    const f32x4 b1 = *(const f32x4*)(bp + kk + 4);
    const f32x4 c0 = *(const f32x4*)(bp + 64 * DIM + kk);
    const f32x4 c1 = *(const f32x4*)(bp + 64 * DIM + kk + 4);
    *(s16x8*)aw  = cvt8(a0, a1);
    *(s16x8*)bw0 = cvt8(b0, b1);
    *(s16x8*)bw1 = cvt8(c0, c1);
    __syncthreads();
    s16x8 af[4], bfr[2];
#pragma unroll
    for (int m = 0; m < 4; ++m)
      af[m] = *(const s16x8*)&As[(m * 16 + lr) * 32 + lg * 8];
#pragma unroll
    for (int n = 0; n < 2; ++n)
      bfr[n] = *(const s16x8*)&Bs[(w * 32 + n * 16 + lr) * 32 + lg * 8];
    if (isV) {
#pragma unroll
      for (int m = 0; m < 4; ++m)
#pragma unroll
        for (int n = 0; n < 2; ++n)
          acc[m][n] = __builtin_amdgcn_mfma_f32_16x16x32_bf16(af[m], bfr[n], acc[m][n], 0, 0, 0);
    } else {
#pragma unroll
      for (int m = 0; m < 4; ++m)
#pragma unroll
        for (int n = 0; n < 2; ++n)
          acc[m][n] = __builtin_amdgcn_mfma_f32_16x16x32_bf16(bfr[n], af[m], acc[m][n], 0, 0, 0);
    }
    __syncthreads();
  }

  if (!isV) {
    // C^T epilogue: acc[m][n][j] = C[x-row = bm*64+m*16+lr]
    //                              [W-col = bn*128+w*32+n*16+lg*4+j]
    const int row0x = bm * 64;
#pragma unroll
    for (int n = 0; n < 2; ++n) {
      const int colb = bn * 128 + w * 32 + n * 16 + lg * 4;   // 4-aligned
      const f32x4 bv4 = *(const f32x4*)&bias[colb];
      const int which = colb >> 10;                           // 0=Q, 1=K
      const int head = (colb & 1023) >> 6;
      const int d0 = colb & 63;                               // 4-aligned
      if (which == 0) {
        short* dst = Qb + head * (L_SEQ * HD);
#pragma unroll
        for (int m = 0; m < 4; ++m) {
          const int xrow = row0x + m * 16 + lr;
          s16x4 wv;
#pragma unroll
          for (int j = 0; j < 4; ++j) wv[j] = f2bf((acc[m][n][j] + bv4[j]) * QSCL);
          *(s16x4*)&dst[xrow * HD + d0] = wv;
        }
      } else {
        short* dst = Kf + head * (L_SEQ * HD);
        const int c = d0 >> 4, khi = (d0 >> 3) & 1, e0 = d0 & 7;  // e0 in {0,4}
#pragma unroll
        for (int m = 0; m < 4; ++m) {
          const int xrow = row0x + m * 16 + lr;
          const int p = xrow >> 5;
          const int lane = khi * 32 + (xrow & 31);
          s16x4 wv;
#pragma unroll
          for (int j = 0; j < 4; ++j) wv[j] = f2bf(acc[m][n][j] + bv4[j]);
          *(s16x4*)&dst[((p * 4 + c) * 64 + lane) * 8 + e0] = wv;
        }
      }
    }
  } else {
    // V normal epilogue -> frag-order store (layout as previous rounds)
#pragma unroll
    for (int n = 0; n < 2; ++n) {
      const int col = bn * 128 + w * 32 + n * 16 + lr;
      const float bv = bias[col];
      const int head = (col & 1023) >> 6;
      const int d = col & 63;
      const int dh = d >> 5;
      const int dq = d & 31;
      short* dst = Vf + head * (L_SEQ * HD);
#pragma unroll
      for (int m = 0; m < 4; ++m) {
        const int rowb = bm * 64 + m * 16 + lg * 4;
        const int tt = rowb >> 6;
        const int kc = (rowb >> 4) & 3;
        const int khi = (rowb >> 3) & 1;
        const int e0 = rowb & 7;
        s16x4 wv;
#pragma unroll
        for (int j = 0; j < 4; ++j) wv[j] = f2bf(acc[m][n][j] + bv);
        *(s16x4*)&dst[(((tt * 4 + kc) * 2 + dh) * 64 + khi * 32 + dq) * 8 + e0] = wv;
      }
    }
  }
}

// ---------------- out-proj GEMM: 64x64 tile, BK=32. Grid 1024, T1 remap. --------
__global__ __launch_bounds__(256) void gemm_out64(const short* __restrict__ A,
                                                  const short* __restrict__ B,
                                                  const float* __restrict__ bias,
                                                  float* __restrict__ C) {
  __shared__ __align__(16) short As[64 * 32];
  __shared__ __align__(16) short Bs[64 * 32];
  const int t = threadIdx.x;
  const int w = t >> 6, l = t & 63;
  const int wr = w >> 1, wc = w & 1;
  const int lr = l & 15, lg = l >> 4;
  const int bid = blockIdx.x;
  const int xcd = bid & 7;
  const int ii = bid >> 3;              // 0..127
  const int bm = xcd * 8 + (ii & 7);    // 0..63
  const int bn = ii >> 3;               // 0..15

  f32x4 acc[2][2];
#pragma unroll
  for (int m = 0; m < 2; ++m)
#pragma unroll
    for (int n = 0; n < 2; ++n) acc[m][n] = (f32x4)0.f;

  const short* aptr = A + (bm * 64 + (t >> 2)) * DIM + (t & 3) * 8;
  const short* bptr = B + (bn * 64 + (t >> 2)) * DIM + (t & 3) * 8;
  short* asl = &As[t * 8];
  short* bsl = &Bs[t * 8];

  for (int kk = 0; kk < DIM; kk += 32) {
    gload_lds16(aptr + kk, asl);
    gload_lds16(bptr + kk, bsl);
    __syncthreads();
    s16x8 af[2], bfr[2];
#pragma unroll
    for (int m = 0; m < 2; ++m)
      af[m] = *(const s16x8*)&As[(wr * 32 + m * 16 + lr) * 32 + lg * 8];
#pragma unroll
    for (int n = 0; n < 2; ++n)
      bfr[n] = *(const s16x8*)&Bs[(wc * 32 + n * 16 + lr) * 32 + lg * 8];
#pragma unroll
    for (int m = 0; m < 2; ++m)
#pragma unroll
      for (int n = 0; n < 2; ++n)
        acc[m][n] = __builtin_amdgcn_mfma_f32_16x16x32_bf16(af[m], bfr[n], acc[m][n], 0, 0, 0);
    __syncthreads();
  }

  const int row0 = bm * 64 + wr * 32;
  const int col0 = bn * 64 + wc * 32;
#pragma unroll
  for (int n = 0; n < 2; ++n) {
    const int col = col0 + n * 16 + lr;
    const float bv = bias[col];
#pragma unroll
    for (int m = 0; m < 2; ++m)
#pragma unroll
      for (int j = 0; j < 4; ++j) {
        const int row = row0 + m * 16 + lg * 4 + j;
        C[row * DIM + col] = acc[m][n][j] + bv;
      }
  }
}

// ---------------- Flash attention: QBLK=64, LDS-shared K/V --------------------
// (round-15 structure; QK chain split into two independent 2-chains + add)
__global__ __launch_bounds__(256, 4) void attn64(const short* __restrict__ Qb,
                                                 const short* __restrict__ Kf,
                                                 const short* __restrict__ Vf,
                                                 short* __restrict__ Ob) {
  __shared__ __align__(16) short KV[2][8192];  // 2 x 16KB: [Kev|Kod|Vev|Vod] x 4KB
  const int bid = blockIdx.x;
  const int xcd = bid & 7;
  const int i = bid >> 3;                       // 0..127
  const int head = (xcd << 1) | (i >> 6);       // 2 heads per XCD
  const int j = i & 63;
  const int qt = (j < 32) ? (63 - j) : (j - 32);  // balanced heavy/light per CU
  const int q0 = qt * 64;
  const int h = threadIdx.x >> 6;               // wave id 0..3
  const int l = threadIdx.x & 63;
  const int q = l & 31;
  const int hi = l >> 5;
  const int sb = h >> 1;                        // q-subtile 0/1
  const int p = h & 1;                          // kt parity

  const short* Qh = Qb + head * (L_SEQ * HD);
  const short* Kh = Kf + head * (L_SEQ * HD);
  const short* Vh = Vf + head * (L_SEQ * HD);
  const short* gKV = (h < 2) ? Kh : Vh;         // this wave's staging source

  s16x8 qf[4];
#pragma unroll
  for (int c = 0; c < 4; ++c)
    qf[c] = *(const s16x8*)&Qh[(q0 + sb * 32 + q) * HD + c * 16 + hi * 8];

  f32x16 o0 = (f32x16)0.f, o1 = (f32x16)0.f;
  f32x4 lvec = (f32x4)0.f;

  const int nr = qt + 1;                        // 64-key rounds

  // prologue: stage round 0 (wave h stages region h: kt = p of K or V)
  {
    const short* gsrc = gKV + p * 2048;
    short* lb = &KV[0][h * 2048];
#pragma unroll
    for (int c = 0; c < 4; ++c) gload_lds16(gsrc + c * 512 + l * 8, lb + c * 512);
  }
  __syncthreads();

  for (int r = 0; r < nr; ++r) {
    const int buf = r & 1;
    if (r + 1 < nr) {                           // stage next round into other buf
      const short* gsrc = gKV + (2 * (r + 1) + p) * 2048;
      short* lb = &KV[buf ^ 1][h * 2048];
#pragma unroll
      for (int c = 0; c < 4; ++c) gload_lds16(gsrc + c * 512 + l * 8, lb + c * 512);
    }

    const bool last = (r == nr - 1);
    if (!(h == 1 && last)) {                    // wave1's last tile fully masked
      const short* kb = &KV[buf][p * 2048];
      const short* vb = &KV[buf][(2 + p) * 2048];

      s16x8 kfr[4];
#pragma unroll
      for (int c = 0; c < 4; ++c)
        kfr[c] = *(const s16x8*)&kb[c * 512 + l * 8];

      // S^T: two independent 2-chains, summed (same math, half the MFMA chain)
      f32x16 s = (f32x16)0.f, s2 = (f32x16)0.f;
      __builtin_amdgcn_s_setprio(1);
      s  = __builtin_amdgcn_mfma_f32_32x32x16_bf16(kfr[0], qf[0], s,  0, 0, 0);
      s2 = __builtin_amdgcn_mfma_f32_32x32x16_bf16(kfr[2], qf[2], s2, 0, 0, 0);
      s  = __builtin_amdgcn_mfma_f32_32x32x16_bf16(kfr[1], qf[1], s,  0, 0, 0);
      s2 = __builtin_amdgcn_mfma_f32_32x32x16_bf16(kfr[3], qf[3], s2, 0, 0, 0);
      __builtin_amdgcn_s_setprio(0);
#pragma unroll
      for (int rr = 0; rr < 16; ++rr) s[rr] += s2[rr];

      // diagonal mask: wave0 (sbA, kt even) / wave3 (sbB, kt odd) on last round
      if (last && (h == 0 || h == 3)) {
        const int qrel = q - hi * 4;
#pragma unroll
        for (int rr = 0; rr < 16; ++rr) {
          const int koff = (rr & 3) + 8 * (rr >> 2);
          if (koff > qrel) s[rr] = -1e30f;
        }
      }

#pragma unroll
      for (int rr = 0; rr < 16; ++rr) s[rr] = exp2_fast(s[rr]);
#pragma unroll
      for (int rr = 0; rr < 16; ++rr) lvec[rr & 3] += s[rr];

#pragma unroll
      for (int cc = 0; cc < 2; ++cc) {
        const int roff = cc * 8;
        const unsigned A = cvt_pk_bf16(s[roff + 0], s[roff + 1]);
        const unsigned B = cvt_pk_bf16(s[roff + 2], s[roff + 3]);
        const unsigned C = cvt_pk_bf16(s[roff + 4], s[roff + 5]);
        const unsigned D = cvt_pk_bf16(s[roff + 6], s[roff + 7]);
        u32x4 pw;
#if HAVE_PLSWAP
        const u32x2 r02 = __builtin_amdgcn_permlane32_swap(A, C, false, false);
        const u32x2 r13 = __builtin_amdgcn_permlane32_swap(B, D, false, false);
        pw[0] = r02[0]; pw[1] = r13[0]; pw[2] = r02[1]; pw[3] = r13[1];
#else
        const unsigned sA = (unsigned)__shfl_xor((int)A, 32, 64);
        const unsigned sB = (unsigned)__shfl_xor((int)B, 32, 64);
        const unsigned sC = (unsigned)__shfl_xor((int)C, 32, 64);
        const unsigned sD = (unsigned)__shfl_xor((int)D, 32, 64);
        pw[0] = hi ? sC : A; pw[1] = hi ? sD : B;
        pw[2] = hi ? C : sA; pw[3] = hi ? D : sB;
#endif
        const s16x8 pf = __builtin_bit_cast(s16x8, pw);
        const s16x8 vf0 = *(const s16x8*)&vb[(cc * 2 + 0) * 512 + l * 8];
        const s16x8 vf1 = *(const s16x8*)&vb[(cc * 2 + 1) * 512 + l * 8];
        __builtin_amdgcn_s_setprio(1);
        o0 = __builtin_amdgcn_mfma_f32_32x32x16_bf16(vf0, pf, o0, 0, 0, 0);
        o1 = __builtin_amdgcn_mfma_f32_32x32x16_bf16(vf1, pf, o1, 0, 0, 0);
        __builtin_amdgcn_s_setprio(0);
      }
    }
    __syncthreads();   // drains this wave's gloads (vmcnt0) + orders buffers
  }

  // per-wave denominator: 4 chains + cross-half exchange
  float lsum = (lvec[0] + lvec[1]) + (lvec[2] + lvec[3]);
  lsum += __shfl_xor(lsum, 32, 64);

  // ---- pairwise merge (same m=0 reference -> plain add). Alias staging LDS. ----
  unsigned* Ms = (unsigned*)&KV[0][0];          // [2][64][17]
  if (p == 1) {                                 // waves 1,3 write partials
    unsigned* st = Ms + (sb * 64 + l) * 17;
#pragma unroll
    for (int w2 = 0; w2 < 8; ++w2) st[w2]     = cvt_pk_bf16(o0[2 * w2], o0[2 * w2 + 1]);
#pragma unroll
    for (int w2 = 0; w2 < 8; ++w2) st[8 + w2] = cvt_pk_bf16(o1[2 * w2], o1[2 * w2 + 1]);
    st[16] = __builtin_bit_cast(unsigned, lsum);
  }
  __syncthreads();
  if (p == 0) {                                 // waves 0,2 combine & write
    const unsigned* st = Ms + (sb * 64 + l) * 17;
    lsum += __builtin_bit_cast(float, st[16]);
#pragma unroll
    for (int w2 = 0; w2 < 8; ++w2) {
      const unsigned ua = st[w2];
      o0[2 * w2]     += __builtin_bit_cast(float, ua << 16);
      o0[2 * w2 + 1] += __builtin_bit_cast(float, ua & 0xffff0000u);
      const unsigned ub = st[8 + w2];
      o1[2 * w2]     += __builtin_bit_cast(float, ub << 16);
      o1[2 * w2 + 1] += __builtin_bit_cast(float, ub & 0xffff0000u);
    }
    const float inv = 1.f / lsum;
    const int orow = q0 + sb * 32 + q;
#pragma unroll
    for (int dh = 0; dh < 2; ++dh) {
#pragma unroll
      for (int tq = 0; tq < 4; ++tq) {
        s16x4 wv;
#pragma unroll
        for (int jj = 0; jj < 4; ++jj) {
          const int rr = tq * 4 + jj;
          const float ov = (dh == 0) ? o0[rr] : o1[rr];
          wv[jj] = f2bf(ov * inv);
        }
        *(s16x4*)&Ob[orow * DIM + head * HD + dh * 32 + tq * 8 + hi * 4] = wv;
      }
    }
  }
}

// ---------------- launch ----------------
extern "C" void kernel_launch(void* const* d_in, const int* in_sizes, int n_in,
                              void* d_out, int out_size, void* d_ws, size_t ws_size,
                              hipStream_t stream) {
  const float* x    = (const float*)d_in[0];
  const float* Wqkv = (const float*)d_in[1];
  const float* bqkv = (const float*)d_in[2];
  const float* Wout = (const float*)d_in[3];
  const float* bout = (const float*)d_in[4];
  float* out = (float*)d_out;

  char* ws = (char*)d_ws;
  short* woutb = (short*)(ws + (14u << 20));      // 2 MB  [D][D] bf16
  short* Qb    = (short*)(ws + (16u << 20));      // 8 MB  [NH][L][64] (pre-scaled)
  short* Kf    = (short*)(ws + (24u << 20));      // 8 MB  frag-order K
  short* Vf    = (short*)(ws + (32u << 20));      // 8 MB  frag-order V
  short* Ob    = (short*)(ws + (40u << 20));      // 8 MB  [L][D] bf16

  cvt_wout<<<CVT_N3 / 256, 256, 0, stream>>>(Wout, woutb);

  gemm_qkv64<<<1536, 256, 0, stream>>>(x, Wqkv, bqkv, Qb, Kf, Vf);
  attn64<<<1024, 256, 0, stream>>>(Qb, Kf, Vf, Ob);
  gemm_out64<<<1024, 256, 0, stream>>>(Ob, woutb, bout, out);
}

// Round 20
// 125.405 us; speedup vs baseline: 1.0963x; 1.0963x over previous
//
#include <hip/hip_runtime.h>
#include <hip/hip_bf16.h>
#include <math.h>

#define L_SEQ 4096
#define DIM   1024
#define NH    16
#define HD    64

// 0.125 * log2(e): folded into Q so QK^T lands in the exp2 domain pre-scaled.
#define QSCL 0.18033688011112042f

typedef __attribute__((ext_vector_type(4)))  float f32x4;
typedef __attribute__((ext_vector_type(16))) float f32x16;
typedef __attribute__((ext_vector_type(8)))  short s16x8;
typedef __attribute__((ext_vector_type(4)))  short s16x4;
typedef __attribute__((ext_vector_type(4)))  unsigned u32x4;
typedef __attribute__((ext_vector_type(2)))  unsigned u32x2;

#if defined(__has_builtin)
#  if __has_builtin(__builtin_amdgcn_permlane32_swap)
#    define HAVE_PLSWAP 1
#  else
#    define HAVE_PLSWAP 0
#  endif
#else
#  define HAVE_PLSWAP 0
#endif

__device__ __forceinline__ short f2bf(float f) {
  unsigned u = __builtin_bit_cast(unsigned, f);
  u = u + 0x7fffu + ((u >> 16) & 1u);   // RNE
  return (short)(u >> 16);
}

__device__ __forceinline__ unsigned cvt_pk_bf16(float lo, float hi_) {
  unsigned r;
  asm("v_cvt_pk_bf16_f32 %0, %1, %2" : "=v"(r) : "v"(lo), "v"(hi_));
  return r;
}

__device__ __forceinline__ float exp2_fast(float x) {
  float r;
  asm("v_exp_f32 %0, %1" : "=v"(r) : "v"(x));
  return r;
}

__device__ __forceinline__ void gload_lds16(const void* g, void* l) {
  __builtin_amdgcn_global_load_lds(
      (__attribute__((address_space(1))) void*)(g),
      (__attribute__((address_space(3))) void*)(l), 16, 0, 0);
}

// ---------------- fused fp32 -> bf16 convert (x, W_qkv, W_out in one launch) ----
#define CVT_N1 (L_SEQ * DIM / 4)        // 1048576
#define CVT_N2 (3 * DIM * DIM / 4)      // 786432
#define CVT_N3 (DIM * DIM / 4)          // 262144

__global__ __launch_bounds__(256) void cvt_all(const float* __restrict__ x,
                                               const float* __restrict__ Wqkv,
                                               const float* __restrict__ Wout,
                                               short* __restrict__ xb,
                                               short* __restrict__ wqkvb,
                                               short* __restrict__ woutb) {
  int i = blockIdx.x * 256 + threadIdx.x;
  const float* src;
  short* dst;
  int j;
  if (i < CVT_N1)               { src = x;    dst = xb;    j = i; }
  else if (i < CVT_N1 + CVT_N2) { src = Wqkv; dst = wqkvb; j = i - CVT_N1; }
  else                          { src = Wout; dst = woutb; j = i - CVT_N1 - CVT_N2; }
  f32x4 f = *(const f32x4*)(src + j * 4);
  s16x4 o;
  o[0] = f2bf(f[0]); o[1] = f2bf(f[1]); o[2] = f2bf(f[2]); o[3] = f2bf(f[3]);
  *(s16x4*)(dst + j * 4) = o;
}

// ---------------- merged QKV projection GEMM: 64x128 tile, 6 blocks/CU ----------
// (round-18 version: bf16 inputs, global_load_lds staging — verified 124.0us)
// Grid 1536 (64 bm x 24 bn), T1 remap: XCD x owns bm in [8x,8x+8) x all bn.
// 4 waves; wave w owns output strip [64 x 32] at n-base w*32. BK=32.
// Q/K (bn 0..15): SWAPPED mfma(bfr, af) -> C^T, vectorized stores.
// V (bn 16..23): normal orientation, frag-order s16x4 stores.
__global__ __launch_bounds__(256) void gemm_qkv64(const short* __restrict__ A,
                                                  const short* __restrict__ B,
                                                  const float* __restrict__ bias,
                                                  short* __restrict__ Qb,
                                                  short* __restrict__ Kf,
                                                  short* __restrict__ Vf) {
  __shared__ __align__(16) short As[64 * 32];    // 4 KB
  __shared__ __align__(16) short Bs[128 * 32];   // 8 KB
  const int t = threadIdx.x;
  const int w = t >> 6, l = t & 63;
  const int lr = l & 15, lg = l >> 4;
  const int bid = blockIdx.x;
  const int xcd = bid & 7;
  const int ii = bid >> 3;              // 0..191
  const int bm = xcd * 8 + (ii & 7);    // 0..63
  const int bn = ii >> 3;               // 0..23
  const bool isV = (bn >= 16);

  f32x4 acc[4][2];
#pragma unroll
  for (int m = 0; m < 4; ++m)
#pragma unroll
    for (int n = 0; n < 2; ++n) acc[m][n] = (f32x4)0.f;

  const short* aptr = A + (bm * 64 + w * 16 + (l >> 2)) * DIM + (l & 3) * 8;
  const short* bptr = B + (bn * 128 + w * 16 + (l >> 2)) * DIM + (l & 3) * 8;
  short* asl = &As[(w * 16) * 32];
  short* bsl = &Bs[(w * 16) * 32];

  for (int kk = 0; kk < DIM; kk += 32) {
    gload_lds16(aptr + kk, asl);
    gload_lds16(bptr + kk, bsl);
    gload_lds16(bptr + kk + 64 * DIM, bsl + 64 * 32);
    __syncthreads();
    s16x8 af[4], bfr[2];
#pragma unroll
    for (int m = 0; m < 4; ++m)
      af[m] = *(const s16x8*)&As[(m * 16 + lr) * 32 + lg * 8];
#pragma unroll
    for (int n = 0; n < 2; ++n)
      bfr[n] = *(const s16x8*)&Bs[(w * 32 + n * 16 + lr) * 32 + lg * 8];
    if (isV) {
#pragma unroll
      for (int m = 0; m < 4; ++m)
#pragma unroll
        for (int n = 0; n < 2; ++n)
          acc[m][n] = __builtin_amdgcn_mfma_f32_16x16x32_bf16(af[m], bfr[n], acc[m][n], 0, 0, 0);
    } else {
#pragma unroll
      for (int m = 0; m < 4; ++m)
#pragma unroll
        for (int n = 0; n < 2; ++n)
          acc[m][n] = __builtin_amdgcn_mfma_f32_16x16x32_bf16(bfr[n], af[m], acc[m][n], 0, 0, 0);
    }
    __syncthreads();
  }

  if (!isV) {
    // C^T epilogue: acc[m][n][j] = C[x-row = bm*64+m*16+lr]
    //                              [W-col = bn*128+w*32+n*16+lg*4+j]
    const int row0x = bm * 64;
#pragma unroll
    for (int n = 0; n < 2; ++n) {
      const int colb = bn * 128 + w * 32 + n * 16 + lg * 4;   // 4-aligned
      const f32x4 bv4 = *(const f32x4*)&bias[colb];
      const int which = colb >> 10;                           // 0=Q, 1=K
      const int head = (colb & 1023) >> 6;
      const int d0 = colb & 63;                               // 4-aligned
      if (which == 0) {
        short* dst = Qb + head * (L_SEQ * HD);
#pragma unroll
        for (int m = 0; m < 4; ++m) {
          const int xrow = row0x + m * 16 + lr;
          s16x4 wv;
#pragma unroll
          for (int j = 0; j < 4; ++j) wv[j] = f2bf((acc[m][n][j] + bv4[j]) * QSCL);
          *(s16x4*)&dst[xrow * HD + d0] = wv;
        }
      } else {
        short* dst = Kf + head * (L_SEQ * HD);
        const int c = d0 >> 4, khi = (d0 >> 3) & 1, e0 = d0 & 7;  // e0 in {0,4}
#pragma unroll
        for (int m = 0; m < 4; ++m) {
          const int xrow = row0x + m * 16 + lr;
          const int p = xrow >> 5;
          const int lane = khi * 32 + (xrow & 31);
          s16x4 wv;
#pragma unroll
          for (int j = 0; j < 4; ++j) wv[j] = f2bf(acc[m][n][j] + bv4[j]);
          *(s16x4*)&dst[((p * 4 + c) * 64 + lane) * 8 + e0] = wv;
        }
      }
    }
  } else {
    // V normal epilogue -> frag-order store (layout as previous rounds)
#pragma unroll
    for (int n = 0; n < 2; ++n) {
      const int col = bn * 128 + w * 32 + n * 16 + lr;
      const float bv = bias[col];
      const int head = (col & 1023) >> 6;
      const int d = col & 63;
      const int dh = d >> 5;
      const int dq = d & 31;
      short* dst = Vf + head * (L_SEQ * HD);
#pragma unroll
      for (int m = 0; m < 4; ++m) {
        const int rowb = bm * 64 + m * 16 + lg * 4;
        const int tt = rowb >> 6;
        const int kc = (rowb >> 4) & 3;
        const int khi = (rowb >> 3) & 1;
        const int e0 = rowb & 7;
        s16x4 wv;
#pragma unroll
        for (int j = 0; j < 4; ++j) wv[j] = f2bf(acc[m][n][j] + bv);
        *(s16x4*)&dst[(((tt * 4 + kc) * 2 + dh) * 64 + khi * 32 + dq) * 8 + e0] = wv;
      }
    }
  }
}

// ---------------- out-proj GEMM: 64x64 tile, BK=32. Grid 1024, T1 remap. --------
__global__ __launch_bounds__(256) void gemm_out64(const short* __restrict__ A,
                                                  const short* __restrict__ B,
                                                  const float* __restrict__ bias,
                                                  float* __restrict__ C) {
  __shared__ __align__(16) short As[64 * 32];
  __shared__ __align__(16) short Bs[64 * 32];
  const int t = threadIdx.x;
  const int w = t >> 6, l = t & 63;
  const int wr = w >> 1, wc = w & 1;
  const int lr = l & 15, lg = l >> 4;
  const int bid = blockIdx.x;
  const int xcd = bid & 7;
  const int ii = bid >> 3;              // 0..127
  const int bm = xcd * 8 + (ii & 7);    // 0..63
  const int bn = ii >> 3;               // 0..15

  f32x4 acc[2][2];
#pragma unroll
  for (int m = 0; m < 2; ++m)
#pragma unroll
    for (int n = 0; n < 2; ++n) acc[m][n] = (f32x4)0.f;

  const short* aptr = A + (bm * 64 + (t >> 2)) * DIM + (t & 3) * 8;
  const short* bptr = B + (bn * 64 + (t >> 2)) * DIM + (t & 3) * 8;
  short* asl = &As[t * 8];
  short* bsl = &Bs[t * 8];

  for (int kk = 0; kk < DIM; kk += 32) {
    gload_lds16(aptr + kk, asl);
    gload_lds16(bptr + kk, bsl);
    __syncthreads();
    s16x8 af[2], bfr[2];
#pragma unroll
    for (int m = 0; m < 2; ++m)
      af[m] = *(const s16x8*)&As[(wr * 32 + m * 16 + lr) * 32 + lg * 8];
#pragma unroll
    for (int n = 0; n < 2; ++n)
      bfr[n] = *(const s16x8*)&Bs[(wc * 32 + n * 16 + lr) * 32 + lg * 8];
#pragma unroll
    for (int m = 0; m < 2; ++m)
#pragma unroll
      for (int n = 0; n < 2; ++n)
        acc[m][n] = __builtin_amdgcn_mfma_f32_16x16x32_bf16(af[m], bfr[n], acc[m][n], 0, 0, 0);
    __syncthreads();
  }

  const int row0 = bm * 64 + wr * 32;
  const int col0 = bn * 64 + wc * 32;
#pragma unroll
  for (int n = 0; n < 2; ++n) {
    const int col = col0 + n * 16 + lr;
    const float bv = bias[col];
#pragma unroll
    for (int m = 0; m < 2; ++m)
#pragma unroll
      for (int j = 0; j < 4; ++j) {
        const int row = row0 + m * 16 + lg * 4 + j;
        C[row * DIM + col] = acc[m][n][j] + bv;
      }
  }
}

// ---------------- Flash attention: QBLK=64, LDS-shared K/V --------------------
// (round-15 structure; QK chain split into two independent 2-chains + add)
__global__ __launch_bounds__(256, 4) void attn64(const short* __restrict__ Qb,
                                                 const short* __restrict__ Kf,
                                                 const short* __restrict__ Vf,
                                                 short* __restrict__ Ob) {
  __shared__ __align__(16) short KV[2][8192];  // 2 x 16KB: [Kev|Kod|Vev|Vod] x 4KB
  const int bid = blockIdx.x;
  const int xcd = bid & 7;
  const int i = bid >> 3;                       // 0..127
  const int head = (xcd << 1) | (i >> 6);       // 2 heads per XCD
  const int j = i & 63;
  const int qt = (j < 32) ? (63 - j) : (j - 32);  // balanced heavy/light per CU
  const int q0 = qt * 64;
  const int h = threadIdx.x >> 6;               // wave id 0..3
  const int l = threadIdx.x & 63;
  const int q = l & 31;
  const int hi = l >> 5;
  const int sb = h >> 1;                        // q-subtile 0/1
  const int p = h & 1;                          // kt parity

  const short* Qh = Qb + head * (L_SEQ * HD);
  const short* Kh = Kf + head * (L_SEQ * HD);
  const short* Vh = Vf + head * (L_SEQ * HD);
  const short* gKV = (h < 2) ? Kh : Vh;         // this wave's staging source

  s16x8 qf[4];
#pragma unroll
  for (int c = 0; c < 4; ++c)
    qf[c] = *(const s16x8*)&Qh[(q0 + sb * 32 + q) * HD + c * 16 + hi * 8];

  f32x16 o0 = (f32x16)0.f, o1 = (f32x16)0.f;
  f32x4 lvec = (f32x4)0.f;

  const int nr = qt + 1;                        // 64-key rounds

  // prologue: stage round 0 (wave h stages region h: kt = p of K or V)
  {
    const short* gsrc = gKV + p * 2048;
    short* lb = &KV[0][h * 2048];
#pragma unroll
    for (int c = 0; c < 4; ++c) gload_lds16(gsrc + c * 512 + l * 8, lb + c * 512);
  }
  __syncthreads();

  for (int r = 0; r < nr; ++r) {
    const int buf = r & 1;
    if (r + 1 < nr) {                           // stage next round into other buf
      const short* gsrc = gKV + (2 * (r + 1) + p) * 2048;
      short* lb = &KV[buf ^ 1][h * 2048];
#pragma unroll
      for (int c = 0; c < 4; ++c) gload_lds16(gsrc + c * 512 + l * 8, lb + c * 512);
    }

    const bool last = (r == nr - 1);
    if (!(h == 1 && last)) {                    // wave1's last tile fully masked
      const short* kb = &KV[buf][p * 2048];
      const short* vb = &KV[buf][(2 + p) * 2048];

      s16x8 kfr[4];
#pragma unroll
      for (int c = 0; c < 4; ++c)
        kfr[c] = *(const s16x8*)&kb[c * 512 + l * 8];

      // S^T: two independent 2-chains, summed (same math, half the MFMA chain)
      f32x16 s = (f32x16)0.f, s2 = (f32x16)0.f;
      __builtin_amdgcn_s_setprio(1);
      s  = __builtin_amdgcn_mfma_f32_32x32x16_bf16(kfr[0], qf[0], s,  0, 0, 0);
      s2 = __builtin_amdgcn_mfma_f32_32x32x16_bf16(kfr[2], qf[2], s2, 0, 0, 0);
      s  = __builtin_amdgcn_mfma_f32_32x32x16_bf16(kfr[1], qf[1], s,  0, 0, 0);
      s2 = __builtin_amdgcn_mfma_f32_32x32x16_bf16(kfr[3], qf[3], s2, 0, 0, 0);
      __builtin_amdgcn_s_setprio(0);
#pragma unroll
      for (int rr = 0; rr < 16; ++rr) s[rr] += s2[rr];

      // diagonal mask: wave0 (sbA, kt even) / wave3 (sbB, kt odd) on last round
      if (last && (h == 0 || h == 3)) {
        const int qrel = q - hi * 4;
#pragma unroll
        for (int rr = 0; rr < 16; ++rr) {
          const int koff = (rr & 3) + 8 * (rr >> 2);
          if (koff > qrel) s[rr] = -1e30f;
        }
      }

#pragma unroll
      for (int rr = 0; rr < 16; ++rr) s[rr] = exp2_fast(s[rr]);
#pragma unroll
      for (int rr = 0; rr < 16; ++rr) lvec[rr & 3] += s[rr];

#pragma unroll
      for (int cc = 0; cc < 2; ++cc) {
        const int roff = cc * 8;
        const unsigned A = cvt_pk_bf16(s[roff + 0], s[roff + 1]);
        const unsigned B = cvt_pk_bf16(s[roff + 2], s[roff + 3]);
        const unsigned C = cvt_pk_bf16(s[roff + 4], s[roff + 5]);
        const unsigned D = cvt_pk_bf16(s[roff + 6], s[roff + 7]);
        u32x4 pw;
#if HAVE_PLSWAP
        const u32x2 r02 = __builtin_amdgcn_permlane32_swap(A, C, false, false);
        const u32x2 r13 = __builtin_amdgcn_permlane32_swap(B, D, false, false);
        pw[0] = r02[0]; pw[1] = r13[0]; pw[2] = r02[1]; pw[3] = r13[1];
#else
        const unsigned sA = (unsigned)__shfl_xor((int)A, 32, 64);
        const unsigned sB = (unsigned)__shfl_xor((int)B, 32, 64);
        const unsigned sC = (unsigned)__shfl_xor((int)C, 32, 64);
        const unsigned sD = (unsigned)__shfl_xor((int)D, 32, 64);
        pw[0] = hi ? sC : A; pw[1] = hi ? sD : B;
        pw[2] = hi ? C : sA; pw[3] = hi ? D : sB;
#endif
        const s16x8 pf = __builtin_bit_cast(s16x8, pw);
        const s16x8 vf0 = *(const s16x8*)&vb[(cc * 2 + 0) * 512 + l * 8];
        const s16x8 vf1 = *(const s16x8*)&vb[(cc * 2 + 1) * 512 + l * 8];
        __builtin_amdgcn_s_setprio(1);
        o0 = __builtin_amdgcn_mfma_f32_32x32x16_bf16(vf0, pf, o0, 0, 0, 0);
        o1 = __builtin_amdgcn_mfma_f32_32x32x16_bf16(vf1, pf, o1, 0, 0, 0);
        __builtin_amdgcn_s_setprio(0);
      }
    }
    __syncthreads();   // drains this wave's gloads (vmcnt0) + orders buffers
  }

  // per-wave denominator: 4 chains + cross-half exchange
  float lsum = (lvec[0] + lvec[1]) + (lvec[2] + lvec[3]);
  lsum += __shfl_xor(lsum, 32, 64);

  // ---- pairwise merge (same m=0 reference -> plain add). Alias staging LDS. ----
  unsigned* Ms = (unsigned*)&KV[0][0];          // [2][64][17]
  if (p == 1) {                                 // waves 1,3 write partials
    unsigned* st = Ms + (sb * 64 + l) * 17;
#pragma unroll
    for (int w2 = 0; w2 < 8; ++w2) st[w2]     = cvt_pk_bf16(o0[2 * w2], o0[2 * w2 + 1]);
#pragma unroll
    for (int w2 = 0; w2 < 8; ++w2) st[8 + w2] = cvt_pk_bf16(o1[2 * w2], o1[2 * w2 + 1]);
    st[16] = __builtin_bit_cast(unsigned, lsum);
  }
  __syncthreads();
  if (p == 0) {                                 // waves 0,2 combine & write
    const unsigned* st = Ms + (sb * 64 + l) * 17;
    lsum += __builtin_bit_cast(float, st[16]);
#pragma unroll
    for (int w2 = 0; w2 < 8; ++w2) {
      const unsigned ua = st[w2];
      o0[2 * w2]     += __builtin_bit_cast(float, ua << 16);
      o0[2 * w2 + 1] += __builtin_bit_cast(float, ua & 0xffff0000u);
      const unsigned ub = st[8 + w2];
      o1[2 * w2]     += __builtin_bit_cast(float, ub << 16);
      o1[2 * w2 + 1] += __builtin_bit_cast(float, ub & 0xffff0000u);
    }
    const float inv = 1.f / lsum;
    const int orow = q0 + sb * 32 + q;
#pragma unroll
    for (int dh = 0; dh < 2; ++dh) {
#pragma unroll
      for (int tq = 0; tq < 4; ++tq) {
        s16x4 wv;
#pragma unroll
        for (int jj = 0; jj < 4; ++jj) {
          const int rr = tq * 4 + jj;
          const float ov = (dh == 0) ? o0[rr] : o1[rr];
          wv[jj] = f2bf(ov * inv);
        }
        *(s16x4*)&Ob[orow * DIM + head * HD + dh * 32 + tq * 8 + hi * 4] = wv;
      }
    }
  }
}

// ---------------- launch ----------------
extern "C" void kernel_launch(void* const* d_in, const int* in_sizes, int n_in,
                              void* d_out, int out_size, void* d_ws, size_t ws_size,
                              hipStream_t stream) {
  const float* x    = (const float*)d_in[0];
  const float* Wqkv = (const float*)d_in[1];
  const float* bqkv = (const float*)d_in[2];
  const float* Wout = (const float*)d_in[3];
  const float* bout = (const float*)d_in[4];
  float* out = (float*)d_out;

  char* ws = (char*)d_ws;
  short* xb    = (short*)(ws);                    // 8 MB  [L][D] bf16
  short* wqkvb = (short*)(ws + (8u  << 20));      // 6 MB  [3D][D] bf16
  short* woutb = (short*)(ws + (14u << 20));      // 2 MB  [D][D] bf16
  short* Qb    = (short*)(ws + (16u << 20));      // 8 MB  [NH][L][64] (pre-scaled)
  short* Kf    = (short*)(ws + (24u << 20));      // 8 MB  frag-order K
  short* Vf    = (short*)(ws + (32u << 20));      // 8 MB  frag-order V
  short* Ob    = (short*)(ws + (40u << 20));      // 8 MB  [L][D] bf16

  cvt_all<<<(CVT_N1 + CVT_N2 + CVT_N3) / 256, 256, 0, stream>>>(x, Wqkv, Wout, xb, wqkvb, woutb);

  gemm_qkv64<<<1536, 256, 0, stream>>>(xb, wqkvb, bqkv, Qb, Kf, Vf);
  attn64<<<1024, 256, 0, stream>>>(Qb, Kf, Vf, Ob);
  gemm_out64<<<1024, 256, 0, stream>>>(Ob, woutb, bout, out);
}

// Round 21
// 123.687 us; speedup vs baseline: 1.1116x; 1.0139x over previous
//
#include <hip/hip_runtime.h>
#include <hip/hip_bf16.h>
#include <math.h>

#define L_SEQ 4096
#define DIM   1024
#define NH    16
#define HD    64

// 0.125 * log2(e): folded into Q so QK^T lands in the exp2 domain pre-scaled.
#define QSCL 0.18033688011112042f

typedef __attribute__((ext_vector_type(4)))  float f32x4;
typedef __attribute__((ext_vector_type(16))) float f32x16;
typedef __attribute__((ext_vector_type(8)))  short s16x8;
typedef __attribute__((ext_vector_type(4)))  short s16x4;
typedef __attribute__((ext_vector_type(4)))  unsigned u32x4;
typedef __attribute__((ext_vector_type(2)))  unsigned u32x2;

#if defined(__has_builtin)
#  if __has_builtin(__builtin_amdgcn_permlane32_swap)
#    define HAVE_PLSWAP 1
#  else
#    define HAVE_PLSWAP 0
#  endif
#else
#  define HAVE_PLSWAP 0
#endif

__device__ __forceinline__ short f2bf(float f) {
  unsigned u = __builtin_bit_cast(unsigned, f);
  u = u + 0x7fffu + ((u >> 16) & 1u);   // RNE
  return (short)(u >> 16);
}

__device__ __forceinline__ unsigned cvt_pk_bf16(float lo, float hi_) {
  unsigned r;
  asm("v_cvt_pk_bf16_f32 %0, %1, %2" : "=v"(r) : "v"(lo), "v"(hi_));
  return r;
}

__device__ __forceinline__ float exp2_fast(float x) {
  float r;
  asm("v_exp_f32 %0, %1" : "=v"(r) : "v"(x));
  return r;
}

__device__ __forceinline__ void gload_lds16(const void* g, void* l) {
  __builtin_amdgcn_global_load_lds(
      (__attribute__((address_space(1))) void*)(g),
      (__attribute__((address_space(3))) void*)(l), 16, 0, 0);
}

// ---------------- fused fp32 -> bf16 convert (x, W_qkv, W_out in one launch) ----
#define CVT_N1 (L_SEQ * DIM / 4)        // 1048576
#define CVT_N2 (3 * DIM * DIM / 4)      // 786432
#define CVT_N3 (DIM * DIM / 4)          // 262144

__global__ __launch_bounds__(256) void cvt_all(const float* __restrict__ x,
                                               const float* __restrict__ Wqkv,
                                               const float* __restrict__ Wout,
                                               short* __restrict__ xb,
                                               short* __restrict__ wqkvb,
                                               short* __restrict__ woutb) {
  int i = blockIdx.x * 256 + threadIdx.x;
  const float* src;
  short* dst;
  int j;
  if (i < CVT_N1)               { src = x;    dst = xb;    j = i; }
  else if (i < CVT_N1 + CVT_N2) { src = Wqkv; dst = wqkvb; j = i - CVT_N1; }
  else                          { src = Wout; dst = woutb; j = i - CVT_N1 - CVT_N2; }
  f32x4 f = *(const f32x4*)(src + j * 4);
  s16x4 o;
  o[0] = f2bf(f[0]); o[1] = f2bf(f[1]); o[2] = f2bf(f[2]); o[3] = f2bf(f[3]);
  *(s16x4*)(dst + j * 4) = o;
}

// ---------------- merged QKV projection GEMM: 64x128 tile, 6 blocks/CU ----------
// (round-18 version: bf16 inputs, global_load_lds staging — verified 124.0us)
// Grid 1536 (64 bm x 24 bn), T1 remap: XCD x owns bm in [8x,8x+8) x all bn.
// 4 waves; wave w owns output strip [64 x 32] at n-base w*32. BK=32.
// Q/K (bn 0..15): SWAPPED mfma(bfr, af) -> C^T, vectorized stores.
// V (bn 16..23): normal orientation, frag-order s16x4 stores.
__global__ __launch_bounds__(256) void gemm_qkv64(const short* __restrict__ A,
                                                  const short* __restrict__ B,
                                                  const float* __restrict__ bias,
                                                  short* __restrict__ Qb,
                                                  short* __restrict__ Kf,
                                                  short* __restrict__ Vf) {
  __shared__ __align__(16) short As[64 * 32];    // 4 KB
  __shared__ __align__(16) short Bs[128 * 32];   // 8 KB
  const int t = threadIdx.x;
  const int w = t >> 6, l = t & 63;
  const int lr = l & 15, lg = l >> 4;
  const int bid = blockIdx.x;
  const int xcd = bid & 7;
  const int ii = bid >> 3;              // 0..191
  const int bm = xcd * 8 + (ii & 7);    // 0..63
  const int bn = ii >> 3;               // 0..23
  const bool isV = (bn >= 16);

  f32x4 acc[4][2];
#pragma unroll
  for (int m = 0; m < 4; ++m)
#pragma unroll
    for (int n = 0; n < 2; ++n) acc[m][n] = (f32x4)0.f;

  const short* aptr = A + (bm * 64 + w * 16 + (l >> 2)) * DIM + (l & 3) * 8;
  const short* bptr = B + (bn * 128 + w * 16 + (l >> 2)) * DIM + (l & 3) * 8;
  short* asl = &As[(w * 16) * 32];
  short* bsl = &Bs[(w * 16) * 32];

  for (int kk = 0; kk < DIM; kk += 32) {
    gload_lds16(aptr + kk, asl);
    gload_lds16(bptr + kk, bsl);
    gload_lds16(bptr + kk + 64 * DIM, bsl + 64 * 32);
    __syncthreads();
    s16x8 af[4], bfr[2];
#pragma unroll
    for (int m = 0; m < 4; ++m)
      af[m] = *(const s16x8*)&As[(m * 16 + lr) * 32 + lg * 8];
#pragma unroll
    for (int n = 0; n < 2; ++n)
      bfr[n] = *(const s16x8*)&Bs[(w * 32 + n * 16 + lr) * 32 + lg * 8];
    if (isV) {
#pragma unroll
      for (int m = 0; m < 4; ++m)
#pragma unroll
        for (int n = 0; n < 2; ++n)
          acc[m][n] = __builtin_amdgcn_mfma_f32_16x16x32_bf16(af[m], bfr[n], acc[m][n], 0, 0, 0);
    } else {
#pragma unroll
      for (int m = 0; m < 4; ++m)
#pragma unroll
        for (int n = 0; n < 2; ++n)
          acc[m][n] = __builtin_amdgcn_mfma_f32_16x16x32_bf16(bfr[n], af[m], acc[m][n], 0, 0, 0);
    }
    __syncthreads();
  }

  if (!isV) {
    // C^T epilogue: acc[m][n][j] = C[x-row = bm*64+m*16+lr]
    //                              [W-col = bn*128+w*32+n*16+lg*4+j]
    const int row0x = bm * 64;
#pragma unroll
    for (int n = 0; n < 2; ++n) {
      const int colb = bn * 128 + w * 32 + n * 16 + lg * 4;   // 4-aligned
      const f32x4 bv4 = *(const f32x4*)&bias[colb];
      const int which = colb >> 10;                           // 0=Q, 1=K
      const int head = (colb & 1023) >> 6;
      const int d0 = colb & 63;                               // 4-aligned
      if (which == 0) {
        short* dst = Qb + head * (L_SEQ * HD);
#pragma unroll
        for (int m = 0; m < 4; ++m) {
          const int xrow = row0x + m * 16 + lr;
          s16x4 wv;
#pragma unroll
          for (int j = 0; j < 4; ++j) wv[j] = f2bf((acc[m][n][j] + bv4[j]) * QSCL);
          *(s16x4*)&dst[xrow * HD + d0] = wv;
        }
      } else {
        short* dst = Kf + head * (L_SEQ * HD);
        const int c = d0 >> 4, khi = (d0 >> 3) & 1, e0 = d0 & 7;  // e0 in {0,4}
#pragma unroll
        for (int m = 0; m < 4; ++m) {
          const int xrow = row0x + m * 16 + lr;
          const int p = xrow >> 5;
          const int lane = khi * 32 + (xrow & 31);
          s16x4 wv;
#pragma unroll
          for (int j = 0; j < 4; ++j) wv[j] = f2bf(acc[m][n][j] + bv4[j]);
          *(s16x4*)&dst[((p * 4 + c) * 64 + lane) * 8 + e0] = wv;
        }
      }
    }
  } else {
    // V normal epilogue -> frag-order store (layout as previous rounds)
#pragma unroll
    for (int n = 0; n < 2; ++n) {
      const int col = bn * 128 + w * 32 + n * 16 + lr;
      const float bv = bias[col];
      const int head = (col & 1023) >> 6;
      const int d = col & 63;
      const int dh = d >> 5;
      const int dq = d & 31;
      short* dst = Vf + head * (L_SEQ * HD);
#pragma unroll
      for (int m = 0; m < 4; ++m) {
        const int rowb = bm * 64 + m * 16 + lg * 4;
        const int tt = rowb >> 6;
        const int kc = (rowb >> 4) & 3;
        const int khi = (rowb >> 3) & 1;
        const int e0 = rowb & 7;
        s16x4 wv;
#pragma unroll
        for (int j = 0; j < 4; ++j) wv[j] = f2bf(acc[m][n][j] + bv);
        *(s16x4*)&dst[(((tt * 4 + kc) * 2 + dh) * 64 + khi * 32 + dq) * 8 + e0] = wv;
      }
    }
  }
}

// ---------------- out-proj GEMM: 64x64 tile, BK=32. Grid 1024, T1 remap. --------
__global__ __launch_bounds__(256) void gemm_out64(const short* __restrict__ A,
                                                  const short* __restrict__ B,
                                                  const float* __restrict__ bias,
                                                  float* __restrict__ C) {
  __shared__ __align__(16) short As[64 * 32];
  __shared__ __align__(16) short Bs[64 * 32];
  const int t = threadIdx.x;
  const int w = t >> 6, l = t & 63;
  const int wr = w >> 1, wc = w & 1;
  const int lr = l & 15, lg = l >> 4;
  const int bid = blockIdx.x;
  const int xcd = bid & 7;
  const int ii = bid >> 3;              // 0..127
  const int bm = xcd * 8 + (ii & 7);    // 0..63
  const int bn = ii >> 3;               // 0..15

  f32x4 acc[2][2];
#pragma unroll
  for (int m = 0; m < 2; ++m)
#pragma unroll
    for (int n = 0; n < 2; ++n) acc[m][n] = (f32x4)0.f;

  const short* aptr = A + (bm * 64 + (t >> 2)) * DIM + (t & 3) * 8;
  const short* bptr = B + (bn * 64 + (t >> 2)) * DIM + (t & 3) * 8;
  short* asl = &As[t * 8];
  short* bsl = &Bs[t * 8];

  for (int kk = 0; kk < DIM; kk += 32) {
    gload_lds16(aptr + kk, asl);
    gload_lds16(bptr + kk, bsl);
    __syncthreads();
    s16x8 af[2], bfr[2];
#pragma unroll
    for (int m = 0; m < 2; ++m)
      af[m] = *(const s16x8*)&As[(wr * 32 + m * 16 + lr) * 32 + lg * 8];
#pragma unroll
    for (int n = 0; n < 2; ++n)
      bfr[n] = *(const s16x8*)&Bs[(wc * 32 + n * 16 + lr) * 32 + lg * 8];
#pragma unroll
    for (int m = 0; m < 2; ++m)
#pragma unroll
      for (int n = 0; n < 2; ++n)
        acc[m][n] = __builtin_amdgcn_mfma_f32_16x16x32_bf16(af[m], bfr[n], acc[m][n], 0, 0, 0);
    __syncthreads();
  }

  const int row0 = bm * 64 + wr * 32;
  const int col0 = bn * 64 + wc * 32;
#pragma unroll
  for (int n = 0; n < 2; ++n) {
    const int col = col0 + n * 16 + lr;
    const float bv = bias[col];
#pragma unroll
    for (int m = 0; m < 2; ++m)
#pragma unroll
      for (int j = 0; j < 4; ++j) {
        const int row = row0 + m * 16 + lg * 4 + j;
        C[row * DIM + col] = acc[m][n][j] + bv;
      }
  }
}

// ---------------- Flash attention: QBLK=64, LDS-shared K/V (round-15/18) --------
// Block = one 64-row qtile, 4 waves: (q-subtile sb = h>>1) x (kt parity p = h&1).
// Per 64-key round: block stages K(2 tiles)+V(2 tiles) = 16KB ONCE into
// double-buffered LDS; both q-subtile waves consume from LDS (halves L2 bytes).
// Fixed softmax reference m=0; pairwise merge (waves 1,3 -> 0,2) via aliased LDS.
// CU balance: qt = (j<32)? 63-j : j-32. Grid 1024; xcd=bid&7 owns 2 heads.
__global__ __launch_bounds__(256, 4) void attn64(const short* __restrict__ Qb,
                                                 const short* __restrict__ Kf,
                                                 const short* __restrict__ Vf,
                                                 short* __restrict__ Ob) {
  __shared__ __align__(16) short KV[2][8192];  // 2 x 16KB: [Kev|Kod|Vev|Vod] x 4KB
  const int bid = blockIdx.x;
  const int xcd = bid & 7;
  const int i = bid >> 3;                       // 0..127
  const int head = (xcd << 1) | (i >> 6);       // 2 heads per XCD
  const int j = i & 63;
  const int qt = (j < 32) ? (63 - j) : (j - 32);  // balanced heavy/light per CU
  const int q0 = qt * 64;
  const int h = threadIdx.x >> 6;               // wave id 0..3
  const int l = threadIdx.x & 63;
  const int q = l & 31;
  const int hi = l >> 5;
  const int sb = h >> 1;                        // q-subtile 0/1
  const int p = h & 1;                          // kt parity

  const short* Qh = Qb + head * (L_SEQ * HD);
  const short* Kh = Kf + head * (L_SEQ * HD);
  const short* Vh = Vf + head * (L_SEQ * HD);
  const short* gKV = (h < 2) ? Kh : Vh;         // this wave's staging source

  s16x8 qf[4];
#pragma unroll
  for (int c = 0; c < 4; ++c)
    qf[c] = *(const s16x8*)&Qh[(q0 + sb * 32 + q) * HD + c * 16 + hi * 8];

  f32x16 o0 = (f32x16)0.f, o1 = (f32x16)0.f;
  f32x4 lvec = (f32x4)0.f;

  const int nr = qt + 1;                        // 64-key rounds

  // prologue: stage round 0 (wave h stages region h: kt = p of K or V)
  {
    const short* gsrc = gKV + p * 2048;
    short* lb = &KV[0][h * 2048];
#pragma unroll
    for (int c = 0; c < 4; ++c) gload_lds16(gsrc + c * 512 + l * 8, lb + c * 512);
  }
  __syncthreads();

  for (int r = 0; r < nr; ++r) {
    const int buf = r & 1;
    if (r + 1 < nr) {                           // stage next round into other buf
      const short* gsrc = gKV + (2 * (r + 1) + p) * 2048;
      short* lb = &KV[buf ^ 1][h * 2048];
#pragma unroll
      for (int c = 0; c < 4; ++c) gload_lds16(gsrc + c * 512 + l * 8, lb + c * 512);
    }

    const bool last = (r == nr - 1);
    if (!(h == 1 && last)) {                    // wave1's last tile fully masked
      const short* kb = &KV[buf][p * 2048];
      const short* vb = &KV[buf][(2 + p) * 2048];

      s16x8 kfr[4];
#pragma unroll
      for (int c = 0; c < 4; ++c)
        kfr[c] = *(const s16x8*)&kb[c * 512 + l * 8];

      f32x16 s = (f32x16)0.f;
      __builtin_amdgcn_s_setprio(1);
#pragma unroll
      for (int c = 0; c < 4; ++c)
        s = __builtin_amdgcn_mfma_f32_32x32x16_bf16(kfr[c], qf[c], s, 0, 0, 0);
      __builtin_amdgcn_s_setprio(0);

      // diagonal mask: wave0 (sbA, kt even) / wave3 (sbB, kt odd) on last round
      if (last && (h == 0 || h == 3)) {
        const int qrel = q - hi * 4;
#pragma unroll
        for (int rr = 0; rr < 16; ++rr) {
          const int koff = (rr & 3) + 8 * (rr >> 2);
          if (koff > qrel) s[rr] = -1e30f;
        }
      }

#pragma unroll
      for (int rr = 0; rr < 16; ++rr) s[rr] = exp2_fast(s[rr]);
#pragma unroll
      for (int rr = 0; rr < 16; ++rr) lvec[rr & 3] += s[rr];

#pragma unroll
      for (int cc = 0; cc < 2; ++cc) {
        const int roff = cc * 8;
        const unsigned A = cvt_pk_bf16(s[roff + 0], s[roff + 1]);
        const unsigned B = cvt_pk_bf16(s[roff + 2], s[roff + 3]);
        const unsigned C = cvt_pk_bf16(s[roff + 4], s[roff + 5]);
        const unsigned D = cvt_pk_bf16(s[roff + 6], s[roff + 7]);
        u32x4 pw;
#if HAVE_PLSWAP
        const u32x2 r02 = __builtin_amdgcn_permlane32_swap(A, C, false, false);
        const u32x2 r13 = __builtin_amdgcn_permlane32_swap(B, D, false, false);
        pw[0] = r02[0]; pw[1] = r13[0]; pw[2] = r02[1]; pw[3] = r13[1];
#else
        const unsigned sA = (unsigned)__shfl_xor((int)A, 32, 64);
        const unsigned sB = (unsigned)__shfl_xor((int)B, 32, 64);
        const unsigned sC = (unsigned)__shfl_xor((int)C, 32, 64);
        const unsigned sD = (unsigned)__shfl_xor((int)D, 32, 64);
        pw[0] = hi ? sC : A; pw[1] = hi ? sD : B;
        pw[2] = hi ? C : sA; pw[3] = hi ? D : sB;
#endif
        const s16x8 pf = __builtin_bit_cast(s16x8, pw);
        const s16x8 vf0 = *(const s16x8*)&vb[(cc * 2 + 0) * 512 + l * 8];
        const s16x8 vf1 = *(const s16x8*)&vb[(cc * 2 + 1) * 512 + l * 8];
        __builtin_amdgcn_s_setprio(1);
        o0 = __builtin_amdgcn_mfma_f32_32x32x16_bf16(vf0, pf, o0, 0, 0, 0);
        o1 = __builtin_amdgcn_mfma_f32_32x32x16_bf16(vf1, pf, o1, 0, 0, 0);
        __builtin_amdgcn_s_setprio(0);
      }
    }
    __syncthreads();   // drains this wave's gloads (vmcnt0) + orders buffers
  }

  // per-wave denominator: 4 chains + cross-half exchange
  float lsum = (lvec[0] + lvec[1]) + (lvec[2] + lvec[3]);
  lsum += __shfl_xor(lsum, 32, 64);

  // ---- pairwise merge (same m=0 reference -> plain add). Alias staging LDS. ----
  unsigned* Ms = (unsigned*)&KV[0][0];          // [2][64][17]
  if (p == 1) {                                 // waves 1,3 write partials
    unsigned* st = Ms + (sb * 64 + l) * 17;
#pragma unroll
    for (int w2 = 0; w2 < 8; ++w2) st[w2]     = cvt_pk_bf16(o0[2 * w2], o0[2 * w2 + 1]);
#pragma unroll
    for (int w2 = 0; w2 < 8; ++w2) st[8 + w2] = cvt_pk_bf16(o1[2 * w2], o1[2 * w2 + 1]);
    st[16] = __builtin_bit_cast(unsigned, lsum);
  }
  __syncthreads();
  if (p == 0) {                                 // waves 0,2 combine & write
    const unsigned* st = Ms + (sb * 64 + l) * 17;
    lsum += __builtin_bit_cast(float, st[16]);
#pragma unroll
    for (int w2 = 0; w2 < 8; ++w2) {
      const unsigned ua = st[w2];
      o0[2 * w2]     += __builtin_bit_cast(float, ua << 16);
      o0[2 * w2 + 1] += __builtin_bit_cast(float, ua & 0xffff0000u);
      const unsigned ub = st[8 + w2];
      o1[2 * w2]     += __builtin_bit_cast(float, ub << 16);
      o1[2 * w2 + 1] += __builtin_bit_cast(float, ub & 0xffff0000u);
    }
    const float inv = 1.f / lsum;
    const int orow = q0 + sb * 32 + q;
#pragma unroll
    for (int dh = 0; dh < 2; ++dh) {
#pragma unroll
      for (int tq = 0; tq < 4; ++tq) {
        s16x4 wv;
#pragma unroll
        for (int jj = 0; jj < 4; ++jj) {
          const int rr = tq * 4 + jj;
          const float ov = (dh == 0) ? o0[rr] : o1[rr];
          wv[jj] = f2bf(ov * inv);
        }
        *(s16x4*)&Ob[orow * DIM + head * HD + dh * 32 + tq * 8 + hi * 4] = wv;
      }
    }
  }
}

// ---------------- launch ----------------
extern "C" void kernel_launch(void* const* d_in, const int* in_sizes, int n_in,
                              void* d_out, int out_size, void* d_ws, size_t ws_size,
                              hipStream_t stream) {
  const float* x    = (const float*)d_in[0];
  const float* Wqkv = (const float*)d_in[1];
  const float* bqkv = (const float*)d_in[2];
  const float* Wout = (const float*)d_in[3];
  const float* bout = (const float*)d_in[4];
  float* out = (float*)d_out;

  char* ws = (char*)d_ws;
  short* xb    = (short*)(ws);                    // 8 MB  [L][D] bf16
  short* wqkvb = (short*)(ws + (8u  << 20));      // 6 MB  [3D][D] bf16
  short* woutb = (short*)(ws + (14u << 20));      // 2 MB  [D][D] bf16
  short* Qb    = (short*)(ws + (16u << 20));      // 8 MB  [NH][L][64] (pre-scaled)
  short* Kf    = (short*)(ws + (24u << 20));      // 8 MB  frag-order K
  short* Vf    = (short*)(ws + (32u << 20));      // 8 MB  frag-order V
  short* Ob    = (short*)(ws + (40u << 20));      // 8 MB  [L][D] bf16

  cvt_all<<<(CVT_N1 + CVT_N2 + CVT_N3) / 256, 256, 0, stream>>>(x, Wqkv, Wout, xb, wqkvb, woutb);

  gemm_qkv64<<<1536, 256, 0, stream>>>(xb, wqkvb, bqkv, Qb, Kf, Vf);
  attn64<<<1024, 256, 0, stream>>>(Qb, Kf, Vf, Ob);
  gemm_out64<<<1024, 256, 0, stream>>>(Ob, woutb, bout, out);
}